// Round 7
// baseline (568.275 us; speedup 1.0000x reference)
//
#include <hip/hip_runtime.h>
#include <hip/hip_bf16.h>
#include <stdint.h>

#define E_   2048
#define HQ_  16
#define HK_  4
#define D_   128
#define G_   4
#define KVE_ 512
#define B_   2
#define N_   2048
#define MTOT (B_*N_)   // 4096

// 1/sqrt(128) * log2(e): exp2-domain softmax (folded into Q projection scale)
#define QSC 0.12751743f

typedef __attribute__((ext_vector_type(8))) short bf16x8;  // 8 bf16 = 4 VGPRs
typedef __attribute__((ext_vector_type(4))) float f32x4;

__device__ __forceinline__ unsigned short f2bf(float f) {
  union { float f; uint32_t u; } a; a.f = f;
  uint32_t u = a.u;
  uint32_t r = (u + 0x7fffu + ((u >> 16) & 1u)) >> 16;  // RNE, inputs finite
  return (unsigned short)r;
}

// truncating bf16 pack of two positive floats (rel err <= 2^-8)
__device__ __forceinline__ uint32_t pack_bf2(float a, float b) {
  union { float f; uint32_t u; } x, y; x.f = a; y.f = b;
  return (x.u >> 16) | (y.u & 0xffff0000u);
}

// RNE-convert 8 contiguous LDS floats -> bf16x8 (v_cvt_pk_bf16_f32 x4).
// Numerically identical to the old cast_all path (both RNE).
__device__ __forceinline__ bf16x8 cvt8(const float* p) {
  float4 a = *(const float4*)p;        // ds_read_b128
  float4 b = *(const float4*)(p + 4);  // ds_read_b128
  union { bf16x8 v; __hip_bfloat162 h[4]; } u;
  u.h[0] = __float22bfloat162_rn(make_float2(a.x, a.y));
  u.h[1] = __float22bfloat162_rn(make_float2(a.z, a.w));
  u.h[2] = __float22bfloat162_rn(make_float2(b.x, b.y));
  u.h[3] = __float22bfloat162_rn(make_float2(b.z, b.w));
  return u.v;
}

// async global->LDS, 16B per lane. LDS dest must be wave-uniform base + lane*16.
__device__ __forceinline__ void g2l16(const void* g, void* l) {
  __builtin_amdgcn_global_load_lds(
      (__attribute__((address_space(1))) void*)(void*)(uintptr_t)g,
      (__attribute__((address_space(3))) void*)l,
      16, 0, 0);
}

// ---------------- fp32 -> bf16 cast, WEIGHTS ONLY ----------------
// Activations (q,k,v) are no longer pre-cast: proj_fused stages them fp32 and
// converts at fragment read (RNE, bit-identical). Saves the 143+48 MB
// activation round-trip (~22 us); this kernel is 75 MB ≈ 12 us.
__global__ void cast_w(const float* __restrict__ wq, const float* __restrict__ wk,
                       const float* __restrict__ wv, const float* __restrict__ wo,
                       unsigned short* __restrict__ dst) {
  int i = blockIdx.x * 256 + threadIdx.x;  // float4 index, grid sized exactly
  const float* src; int base;
  if      (i < 1048576) { src = wq; base = 0; }
  else if (i < 1310720) { src = wk; base = 1048576; }
  else if (i < 1572864) { src = wv; base = 1310720; }
  else                  { src = wo; base = 1572864; }
  float4 val = ((const float4*)src)[i - base];
  ushort4 o;
  o.x = f2bf(val.x); o.y = f2bf(val.y); o.z = f2bf(val.z); o.w = f2bf(val.w);
  ((ushort4*)dst)[i] = o;
}

// ---------------- proj K-loop: fp32-A staging, bf16-W, 2-phase dbuf ----------
// Same R4-verified 2-phase schedule; A-side staged as fp32 (16 KB/buf, 4
// g2l16/thread), fragments converted via cvt8 (~32 cyc/wave/iter vs 310 MFMA).
// LDS 48 KB -> 3 blocks/CU preserved.
__device__ __forceinline__ void kloop_f32A(const float* __restrict__ A,
                                           const unsigned short* __restrict__ W,
                                           float* Asf, unsigned short* Bs,
                                           int bm, int bn,
                                           int wm, int wn, int tid, int l16, int quad,
                                           f32x4 acc[4][4]) {
  auto stage = [&](int k0, int buf) {
    float* Ad = Asf + buf * 4096;
    unsigned short* Bd = Bs + buf * 4096;
#pragma unroll
    for (int r = 0; r < 4; ++r) {           // A: 128 rows x 32 floats = 1024 slots
      int c = r * 256 + tid;
      int row = c >> 3, c4 = (c & 7) << 2;
      g2l16(A + (size_t)(bm + row) * E_ + k0 + c4, (char*)Ad + (size_t)c * 16);
    }
#pragma unroll
    for (int r = 0; r < 2; ++r) {           // W: 128 rows x 32 bf16 = 512 slots
      int c = r * 256 + tid;
      int row = c >> 2, c8 = (c & 3) << 3;
      g2l16(W + (size_t)(bn + row) * E_ + k0 + c8, (char*)Bd + (size_t)c * 16);
    }
  };

  stage(0, 0);
  __syncthreads();  // prologue drain: buf0 ready

  for (int t = 0; t < 64; ++t) {
    if (t + 1 < 64) stage((t + 1) << 5, (t + 1) & 1);  // async prefetch

    const float* Ab = Asf + (t & 1) * 4096;
    const unsigned short* Bb = Bs + (t & 1) * 4096;
    bf16x8 af[4], bf[4];
#pragma unroll
    for (int mi = 0; mi < 4; ++mi)
      af[mi] = cvt8(Ab + (wm + mi * 16 + l16) * 32 + quad * 8);
#pragma unroll
    for (int ni = 0; ni < 4; ++ni)
      bf[ni] = *(const bf16x8*)(Bb + (wn + ni * 16 + l16) * 32 + quad * 8);
#pragma unroll
    for (int mi = 0; mi < 4; ++mi)
#pragma unroll
      for (int ni = 0; ni < 4; ++ni)
        acc[mi][ni] = __builtin_amdgcn_mfma_f32_16x16x32_bf16(af[mi], bf[ni], acc[mi][ni], 0, 0, 0);

    __syncthreads();  // drains prefetch + all reads of buf[t&1] done
  }
}

// ---------------- bf16 GEMM K-loop (R4-verified, used by gemm_out) ----------
__device__ __forceinline__ void gemm_kloop(const unsigned short* __restrict__ A,
                                           const unsigned short* __restrict__ W,
                                           unsigned short* As, unsigned short* Bs,
                                           int bm, int bn, int K,
                                           int wm, int wn, int tid, int l16, int quad,
                                           f32x4 acc[4][4]) {
  auto stage = [&](int k0, int buf) {
    unsigned short* Ad = As + buf * 4096;
    unsigned short* Bd = Bs + buf * 4096;
#pragma unroll
    for (int r = 0; r < 2; ++r) {
      int c = r * 256 + tid;
      int row = c >> 2, c8 = (c & 3) << 3;
      g2l16(A + (size_t)(bm + row) * K + k0 + c8, (char*)Ad + (size_t)c * 16);
    }
#pragma unroll
    for (int r = 0; r < 2; ++r) {
      int c = r * 256 + tid;
      int row = c >> 2, c8 = (c & 3) << 3;
      g2l16(W + (size_t)(bn + row) * K + k0 + c8, (char*)Bd + (size_t)c * 16);
    }
  };

  stage(0, 0);
  __syncthreads();  // prologue drain: buf0 ready

  const int niter = K >> 5;
  for (int t = 0; t < niter; ++t) {
    if (t + 1 < niter) stage((t + 1) << 5, (t + 1) & 1);  // async prefetch

    const unsigned short* Ab = As + (t & 1) * 4096;
    const unsigned short* Bb = Bs + (t & 1) * 4096;
    bf16x8 af[4], bf[4];
#pragma unroll
    for (int mi = 0; mi < 4; ++mi)
      af[mi] = *(const bf16x8*)(Ab + (wm + mi * 16 + l16) * 32 + quad * 8);
#pragma unroll
    for (int ni = 0; ni < 4; ++ni)
      bf[ni] = *(const bf16x8*)(Bb + (wn + ni * 16 + l16) * 32 + quad * 8);
#pragma unroll
    for (int mi = 0; mi < 4; ++mi)
#pragma unroll
      for (int ni = 0; ni < 4; ++ni)
        acc[mi][ni] = __builtin_amdgcn_mfma_f32_16x16x32_bf16(af[mi], bf[ni], acc[mi][ni], 0, 0, 0);

    __syncthreads();  // drains prefetch + all reads of buf[t&1] done
  }
}

// ---------------- fused Q/K/V projection (fp32 activations in) ----------------
__global__ __launch_bounds__(256, 3)
void proj_fused(const float* __restrict__ query, const float* __restrict__ key,
                const float* __restrict__ value,
                const unsigned short* __restrict__ Wqb, const unsigned short* __restrict__ Wkb,
                const unsigned short* __restrict__ Wvb,
                const float* __restrict__ bq, const float* __restrict__ bk,
                const float* __restrict__ bv,
                unsigned short* __restrict__ Qb, unsigned short* __restrict__ Kpp,
                unsigned short* __restrict__ Vtt) {
  __shared__ float          Asf[2 * 128 * 32];  // fp32 A double buffer: 32 KB
  __shared__ unsigned short Bs[2 * 128 * 32];   // bf16 W double buffer: 16 KB
  const int tid  = threadIdx.x;
  const int wave = tid >> 6, lane = tid & 63;
  const int l16  = lane & 15, quad = lane >> 4;
  const int bm = blockIdx.x * 128;
  const int wm = (wave & 1) * 64, wn = (wave >> 1) * 64;
  const int y = blockIdx.y;

  const float *A;
  const unsigned short *W;
  const float* bias;
  unsigned short* out;
  int bn, mode, Nn;
  float scale;
  if (y < 16)      { A = query; W = Wqb; bias = bq; out = Qb;  bn = y * 128;        mode = 0; Nn = 2048; scale = QSC;  }
  else if (y < 20) { A = key;   W = Wkb; bias = bk; out = Kpp; bn = (y - 16) * 128; mode = 0; Nn = 512;  scale = 1.0f; }
  else             { A = value; W = Wvb; bias = bv; out = Vtt; bn = (y - 20) * 128; mode = 1; Nn = 512;  scale = 1.0f; }

  f32x4 acc[4][4] = {};
  kloop_f32A(A, W, Asf, Bs, bm, bn, wm, wn, tid, l16, quad, acc);

  if (mode == 0) {
#pragma unroll
    for (int mi = 0; mi < 4; ++mi)
#pragma unroll
      for (int ni = 0; ni < 4; ++ni) {
        int col = bn + wn + ni * 16 + l16;
        float bb = bias[col];
        int row0 = bm + wm + mi * 16 + quad * 4;
#pragma unroll
        for (int r = 0; r < 4; ++r)
          out[(size_t)(row0 + r) * Nn + col] = f2bf((acc[mi][ni][r] + bb) * scale);
      }
  } else {  // V: transposed per batch -> Vt[(b*KVE + col)*N + s]
#pragma unroll
    for (int mi = 0; mi < 4; ++mi)
#pragma unroll
      for (int ni = 0; ni < 4; ++ni) {
        int col = bn + wn + ni * 16 + l16;
        float bb = bias[col];
        int row0 = bm + wm + mi * 16 + quad * 4;
        int b = row0 >> 11, s = row0 & 2047;
        ushort4 o;
        o.x = f2bf(acc[mi][ni][0] + bb);
        o.y = f2bf(acc[mi][ni][1] + bb);
        o.z = f2bf(acc[mi][ni][2] + bb);
        o.w = f2bf(acc[mi][ni][3] + bb);
        *(ushort4*)(out + (size_t)(b * KVE_ + col) * N_ + s) = o;
      }
  }
}

// ---------------- output projection (fp32 out, R4-verified) ----------------
__global__ __launch_bounds__(256, 3)
void gemm_out(const unsigned short* __restrict__ A, const unsigned short* __restrict__ W,
              const float* __restrict__ bias, float* __restrict__ Cout) {
  __shared__ unsigned short As[2 * 128 * 32];
  __shared__ unsigned short Bs[2 * 128 * 32];
  const int tid  = threadIdx.x;
  const int wave = tid >> 6, lane = tid & 63;
  const int l16  = lane & 15, quad = lane >> 4;
  const int bm = blockIdx.x * 128, bn = blockIdx.y * 128;
  const int wm = (wave & 1) * 64, wn = (wave >> 1) * 64;

  f32x4 acc[4][4] = {};
  gemm_kloop(A, W, As, Bs, bm, bn, E_, wm, wn, tid, l16, quad, acc);

#pragma unroll
  for (int mi = 0; mi < 4; ++mi)
#pragma unroll
    for (int ni = 0; ni < 4; ++ni) {
      int col = bn + wn + ni * 16 + l16;
      float bb = bias[col];
      int row0 = bm + wm + mi * 16 + quad * 4;
#pragma unroll
      for (int r = 0; r < 4; ++r)
        Cout[(size_t)(row0 + r) * E_ + col] = acc[mi][ni][r] + bb;
    }
}

// ---------------- Flash attention (R6-verified: R1 structure + T5 setprio) ----
// 32-key KV tiles, LDS 32 KB, each wave owns 16 q rows x full key range.
// Grid (32,32); launch_bounds(256,4). Measured: 81.4 us, VGPR 56, no spill.
__global__ __launch_bounds__(256, 4)
void attn_gqa(const unsigned short* __restrict__ Qp,
              const unsigned short* __restrict__ Kp,
              const unsigned short* __restrict__ Vt,
              unsigned short* __restrict__ Ob,
              const int* __restrict__ is_causal_p) {
  __shared__ unsigned short lds[2][8192];  // [buf][ K:4096 shorts | V:4096 shorts ] = 32KB

  const int tid  = threadIdx.x;
  const int wave = tid >> 6, lane = tid & 63;
  const int l16  = lane & 15, quad = lane >> 4;
  const int bh = blockIdx.y;
  const int u  = (blockIdx.x + bh) & 31;
  const int qt = (u < 16) ? u : 47 - u;   // 64-row q-tile; balanced per-CU sum
  const int b = bh >> 4, hq = bh & 15, hk = hq >> 2;
  const int causal = *is_causal_p;

  const unsigned short* Kbase = Kp + (size_t)b * N_ * KVE_ + hk * D_;
  const unsigned short* Vbase = Vt + (size_t)(b * KVE_ + hk * D_) * N_;

  const int nt = causal ? 2 * qt + 2 : (N_ / 32);  // 32-key tiles
  const int qw = qt * 64 + wave * 16;              // wave's 16-q window start

  auto stage = [&](int t, int buf) {
    int s0 = t * 32;
    unsigned short* Kd = &lds[buf][0];
    unsigned short* Vd = &lds[buf][4096];
#pragma unroll
    for (int r = 0; r < 2; ++r) {
      int idx = r * 256 + tid;
      int s = (idx >> 8) * 16 + (idx & 15);
      int d = ((idx >> 6) & 3) * 32 + ((idx >> 4) & 3) * 8;
      g2l16(Kbase + (size_t)(s0 + s) * KVE_ + d, Kd + (size_t)idx * 8);
    }
#pragma unroll
    for (int r = 0; r < 2; ++r) {
      int idx = r * 256 + tid;
      int d = (idx >> 6) * 16 + (idx & 15);
      int sc = ((idx >> 4) & 3) * 8;
      g2l16(Vbase + (size_t)d * N_ + s0 + sc, Vd + (size_t)idx * 8);
    }
  };

  // Q fragments (B-operand: n=l16 -> q, k=quad*8+j -> d), exp2-scaled already
  bf16x8 qf[4];
#pragma unroll
  for (int kk = 0; kk < 4; ++kk)
    qf[kk] = *(const bf16x8*)(Qp + (size_t)(b * N_ + qw + l16) * E_ +
                              hq * D_ + kk * 32 + quad * 8);

  f32x4 o[8] = {};
  float tsum = 0.f;

  stage(0, 0);
  __syncthreads();

  for (int t = 0; t < nt; ++t) {
    if (t + 1 < nt) stage(t + 1, (t + 1) & 1);  // overlaps compute(t)
    const unsigned short* Kb = &lds[t & 1][0];
    const unsigned short* Vb = &lds[t & 1][4096];
    const int sw = t * 32;
    const bool active = !causal || (sw <= qw + 15);  // wave-uniform

    if (active) {
      // S^T = K Q^T : rows s = sw + ni*16+quad*4+r, cols q = qw + l16
      f32x4 sa[2] = {};
      __builtin_amdgcn_s_setprio(1);
#pragma unroll
      for (int kk = 0; kk < 4; ++kk) {
        bf16x8 kf0 = *(const bf16x8*)(Kb + ((kk)     * 64 + lane) * 8);
        bf16x8 kf1 = *(const bf16x8*)(Kb + ((4 + kk) * 64 + lane) * 8);
        sa[0] = __builtin_amdgcn_mfma_f32_16x16x32_bf16(kf0, qf[kk], sa[0], 0, 0, 0);
        sa[1] = __builtin_amdgcn_mfma_f32_16x16x32_bf16(kf1, qf[kk], sa[1], 0, 0, 0);
      }
      __builtin_amdgcn_s_setprio(0);

      if (causal && sw + 31 > qw) {  // diagonal overlap: mask s > q
        int q = qw + l16;
#pragma unroll
        for (int ni = 0; ni < 2; ++ni) {
          int sbase = sw + ni * 16 + quad * 4;
#pragma unroll
          for (int r = 0; r < 4; ++r)
            if (sbase + r > q) sa[ni][r] = -3.0e38f;
        }
      }

      // P = exp2(S) (no max subtraction), pack to bf16 pairs in-register
      uint32_t pk[2][2];
#pragma unroll
      for (int ni = 0; ni < 2; ++ni) {
#pragma unroll
        for (int r = 0; r < 4; ++r) {
          float e = __builtin_amdgcn_exp2f(sa[ni][r]);
          tsum += e;
          sa[ni][r] = e;
        }
        pk[ni][0] = pack_bf2(sa[ni][0], sa[ni][1]);
        pk[ni][1] = pack_bf2(sa[ni][2], sa[ni][3]);
      }

      // B-operand P[k=quad*8+j][n=l16] via shuffle network (unchanged mapping)
      union { bf16x8 v; uint32_t w[4]; } pb;
#pragma unroll
      for (int h = 0; h < 4; ++h) {
        int src = ((quad & 1) * 2 + (h >> 1)) * 16 + l16;
        uint32_t v0 = __shfl(pk[0][h & 1], src);
        uint32_t v1 = __shfl(pk[1][h & 1], src);
        pb.w[h] = (quad & 2) ? v1 : v0;
      }

      // O^T += V^T[:, sw:sw+32] P^T[sw:sw+32, :] — one K=32 MFMA step per d-block
      bf16x8 vf[8];
#pragma unroll
      for (int n8 = 0; n8 < 8; ++n8)
        vf[n8] = *(const bf16x8*)(Vb + (n8 * 64 + lane) * 8);
      __builtin_amdgcn_s_setprio(1);
#pragma unroll
      for (int n8 = 0; n8 < 8; ++n8)
        o[n8] = __builtin_amdgcn_mfma_f32_16x16x32_bf16(vf[n8], pb.v, o[n8], 0, 0, 0);
      __builtin_amdgcn_s_setprio(0);
    }
    __syncthreads();  // drains stage(t+1); protects buffer reuse
  }

  // ---- epilogue: pure-register; full row-sum via quad reduction ----
  float lt = tsum;
  lt += __shfl_xor(lt, 16);
  lt += __shfl_xor(lt, 32);
  float inv = 1.0f / lt;
  int q = qw + l16;
#pragma unroll
  for (int n8 = 0; n8 < 8; ++n8) {
    ushort4 st;
    st.x = f2bf(o[n8][0] * inv);
    st.y = f2bf(o[n8][1] * inv);
    st.z = f2bf(o[n8][2] * inv);
    st.w = f2bf(o[n8][3] * inv);
    *(ushort4*)(Ob + (size_t)(b * N_ + q) * E_ + hq * D_ + n8 * 16 + quad * 4) = st;
  }
}

// ---------------- host ----------------
extern "C" void kernel_launch(void* const* d_in, const int* in_sizes, int n_in,
                              void* d_out, int out_size, void* d_ws, size_t ws_size,
                              hipStream_t stream) {
  const float* query = (const float*)d_in[0];
  const float* key   = (const float*)d_in[1];
  const float* value = (const float*)d_in[2];
  const float* Wq = (const float*)d_in[3];
  const float* bq = (const float*)d_in[4];
  const float* Wk = (const float*)d_in[5];
  const float* bk = (const float*)d_in[6];
  const float* Wv = (const float*)d_in[7];
  const float* bv = (const float*)d_in[8];
  const float* Wo = (const float*)d_in[9];
  const float* bo = (const float*)d_in[10];
  const int* is_causal = (const int*)d_in[11];

  char* ws = (char*)d_ws;
  size_t off = 0;
  auto alloc = [&](size_t bytes) {
    char* p = ws + off;
    off += (bytes + 255) & ~(size_t)255;
    return p;
  };
  // NOTE: Wqb..Wob must stay contiguous in this order (cast_w writes one region)
  unsigned short* Wqb = (unsigned short*)alloc((size_t)E_ * E_ * 2);
  unsigned short* Wkb = (unsigned short*)alloc((size_t)KVE_ * E_ * 2);
  unsigned short* Wvb = (unsigned short*)alloc((size_t)KVE_ * E_ * 2);
  unsigned short* Wob = (unsigned short*)alloc((size_t)E_ * E_ * 2);
  unsigned short* Qb  = (unsigned short*)alloc((size_t)MTOT * E_ * 2);
  unsigned short* Kpp = (unsigned short*)alloc((size_t)MTOT * KVE_ * 2);
  unsigned short* Vtt = (unsigned short*)alloc((size_t)MTOT * KVE_ * 2);
  unsigned short* Ob  = (unsigned short*)alloc((size_t)MTOT * E_ * 2);
  (void)ws_size; (void)n_in; (void)in_sizes; (void)out_size;

  dim3 blk(256);
  cast_w<<<dim3(10240), blk, 0, stream>>>(Wq, Wk, Wv, Wo, Wqb);
  proj_fused<<<dim3(32, 24), blk, 0, stream>>>(query, key, value, Wqb, Wkb, Wvb,
                                               bq, bk, bv, Qb, Kpp, Vtt);
  attn_gqa<<<dim3(32, 32), blk, 0, stream>>>(Qb, Kpp, Vtt, Ob, is_causal);
  gemm_out<<<dim3(32, 16), blk, 0, stream>>>(Ob, Wob, bo, (float*)d_out);
}

// Round 8
// 401.538 us; speedup vs baseline: 1.4152x; 1.4152x over previous
//
#include <hip/hip_runtime.h>
#include <hip/hip_bf16.h>
#include <stdint.h>

#define E_   2048
#define HQ_  16
#define HK_  4
#define D_   128
#define G_   4
#define KVE_ 512
#define B_   2
#define N_   2048
#define MTOT (B_*N_)   // 4096

// 1/sqrt(128) * log2(e): exp2-domain softmax (folded into Q projection scale)
#define QSC 0.12751743f

typedef __attribute__((ext_vector_type(8))) short bf16x8;  // 8 bf16 = 4 VGPRs
typedef __attribute__((ext_vector_type(4))) float f32x4;

__device__ __forceinline__ unsigned short f2bf(float f) {
  union { float f; uint32_t u; } a; a.f = f;
  uint32_t u = a.u;
  uint32_t r = (u + 0x7fffu + ((u >> 16) & 1u)) >> 16;  // RNE, inputs finite
  return (unsigned short)r;
}

// truncating bf16 pack of two positive floats (rel err <= 2^-8)
__device__ __forceinline__ uint32_t pack_bf2(float a, float b) {
  union { float f; uint32_t u; } x, y; x.f = a; y.f = b;
  return (x.u >> 16) | (y.u & 0xffff0000u);
}

// RNE-convert two float4s (logical elems 0-3, 4-7) -> bf16x8.
// Numerically identical to the old cast_all path (both RNE).
__device__ __forceinline__ bf16x8 cvt8p(float4 a, float4 b) {
  union { bf16x8 v; __hip_bfloat162 h[4]; } u;
  u.h[0] = __float22bfloat162_rn(make_float2(a.x, a.y));
  u.h[1] = __float22bfloat162_rn(make_float2(a.z, a.w));
  u.h[2] = __float22bfloat162_rn(make_float2(b.x, b.y));
  u.h[3] = __float22bfloat162_rn(make_float2(b.z, b.w));
  return u.v;
}

// async global->LDS, 16B per lane. LDS dest must be wave-uniform base + lane*16.
__device__ __forceinline__ void g2l16(const void* g, void* l) {
  __builtin_amdgcn_global_load_lds(
      (__attribute__((address_space(1))) void*)(void*)(uintptr_t)g,
      (__attribute__((address_space(3))) void*)l,
      16, 0, 0);
}

// ---------------- fp32 -> bf16 cast, WEIGHTS ONLY ----------------
__global__ void cast_w(const float* __restrict__ wq, const float* __restrict__ wk,
                       const float* __restrict__ wv, const float* __restrict__ wo,
                       unsigned short* __restrict__ dst) {
  int i = blockIdx.x * 256 + threadIdx.x;  // float4 index, grid sized exactly
  const float* src; int base;
  if      (i < 1048576) { src = wq; base = 0; }
  else if (i < 1310720) { src = wk; base = 1048576; }
  else if (i < 1572864) { src = wv; base = 1310720; }
  else                  { src = wo; base = 1572864; }
  float4 val = ((const float4*)src)[i - base];
  ushort4 o;
  o.x = f2bf(val.x); o.y = f2bf(val.y); o.z = f2bf(val.z); o.w = f2bf(val.w);
  ((ushort4*)dst)[i] = o;
}

// ---------------- proj K-loop: fp32-A staging (XOR-swizzled), bf16-W ----------
// R7's fp32 A rows are 128 B = exactly 32 banks -> the fragment read was a
// 16-way bank conflict (SQ_LDS_BANK_CONFLICT 1.4e8, +230 us). Fix per rule
// #21 (both-sides-or-neither with global_load_lds): LDS dest stays LINEAR,
// the global SOURCE slot is pre-swizzled by (slot ^ (row&7)), and the read
// applies the same involution. Lanes l16=0..15 then hit 8 distinct 4-bank
// groups, 2 lanes each -> 2-way = free (m136).
__device__ __forceinline__ void kloop_f32A(const float* __restrict__ A,
                                           const unsigned short* __restrict__ W,
                                           float* Asf, unsigned short* Bs,
                                           int bm, int bn,
                                           int wm, int wn, int tid, int l16, int quad,
                                           f32x4 acc[4][4]) {
  auto stage = [&](int k0, int buf) {
    float* Ad = Asf + buf * 4096;
    unsigned short* Bd = Bs + buf * 4096;
#pragma unroll
    for (int r = 0; r < 4; ++r) {           // A: 128 rows x 8 16B-slots = 1024
      int c = r * 256 + tid;
      int row = c >> 3;
      int c4 = (((c & 7) ^ (row & 7)) << 2);   // pre-swizzled global source slot
      g2l16(A + (size_t)(bm + row) * E_ + k0 + c4, (char*)Ad + (size_t)c * 16);
    }
#pragma unroll
    for (int r = 0; r < 2; ++r) {           // W: 128 rows x 32 bf16 = 512 slots
      int c = r * 256 + tid;
      int row = c >> 2, c8 = (c & 3) << 3;
      g2l16(W + (size_t)(bn + row) * E_ + k0 + c8, (char*)Bd + (size_t)c * 16);
    }
  };

  stage(0, 0);
  __syncthreads();  // prologue drain: buf0 ready

  const int r7 = l16 & 7;  // (row & 7) for fragment rows wm+mi*16+l16
  for (int t = 0; t < 64; ++t) {
    if (t + 1 < 64) stage((t + 1) << 5, (t + 1) & 1);  // async prefetch

    const float* Ab = Asf + (t & 1) * 4096;
    const unsigned short* Bb = Bs + (t & 1) * 4096;
    bf16x8 af[4], bf[4];
#pragma unroll
    for (int mi = 0; mi < 4; ++mi) {
      const float* Ar = Ab + (wm + mi * 16 + l16) * 32;
      float4 a = *(const float4*)(Ar + ((((quad << 1) | 0) ^ r7) << 2));  // logical slot 2q
      float4 b = *(const float4*)(Ar + ((((quad << 1) | 1) ^ r7) << 2));  // logical slot 2q+1
      af[mi] = cvt8p(a, b);
    }
#pragma unroll
    for (int ni = 0; ni < 4; ++ni)
      bf[ni] = *(const bf16x8*)(Bb + (wn + ni * 16 + l16) * 32 + quad * 8);
#pragma unroll
    for (int mi = 0; mi < 4; ++mi)
#pragma unroll
      for (int ni = 0; ni < 4; ++ni)
        acc[mi][ni] = __builtin_amdgcn_mfma_f32_16x16x32_bf16(af[mi], bf[ni], acc[mi][ni], 0, 0, 0);

    __syncthreads();  // drains prefetch + all reads of buf[t&1] done
  }
}

// ---------------- bf16 GEMM K-loop (R4-verified, used by gemm_out) ----------
__device__ __forceinline__ void gemm_kloop(const unsigned short* __restrict__ A,
                                           const unsigned short* __restrict__ W,
                                           unsigned short* As, unsigned short* Bs,
                                           int bm, int bn, int K,
                                           int wm, int wn, int tid, int l16, int quad,
                                           f32x4 acc[4][4]) {
  auto stage = [&](int k0, int buf) {
    unsigned short* Ad = As + buf * 4096;
    unsigned short* Bd = Bs + buf * 4096;
#pragma unroll
    for (int r = 0; r < 2; ++r) {
      int c = r * 256 + tid;
      int row = c >> 2, c8 = (c & 3) << 3;
      g2l16(A + (size_t)(bm + row) * K + k0 + c8, (char*)Ad + (size_t)c * 16);
    }
#pragma unroll
    for (int r = 0; r < 2; ++r) {
      int c = r * 256 + tid;
      int row = c >> 2, c8 = (c & 3) << 3;
      g2l16(W + (size_t)(bn + row) * K + k0 + c8, (char*)Bd + (size_t)c * 16);
    }
  };

  stage(0, 0);
  __syncthreads();  // prologue drain: buf0 ready

  const int niter = K >> 5;
  for (int t = 0; t < niter; ++t) {
    if (t + 1 < niter) stage((t + 1) << 5, (t + 1) & 1);  // async prefetch

    const unsigned short* Ab = As + (t & 1) * 4096;
    const unsigned short* Bb = Bs + (t & 1) * 4096;
    bf16x8 af[4], bf[4];
#pragma unroll
    for (int mi = 0; mi < 4; ++mi)
      af[mi] = *(const bf16x8*)(Ab + (wm + mi * 16 + l16) * 32 + quad * 8);
#pragma unroll
    for (int ni = 0; ni < 4; ++ni)
      bf[ni] = *(const bf16x8*)(Bb + (wn + ni * 16 + l16) * 32 + quad * 8);
#pragma unroll
    for (int mi = 0; mi < 4; ++mi)
#pragma unroll
      for (int ni = 0; ni < 4; ++ni)
        acc[mi][ni] = __builtin_amdgcn_mfma_f32_16x16x32_bf16(af[mi], bf[ni], acc[mi][ni], 0, 0, 0);

    __syncthreads();  // drains prefetch + all reads of buf[t&1] done
  }
}

// ---------------- fused Q/K/V projection (fp32 activations in) ----------------
__global__ __launch_bounds__(256, 3)
void proj_fused(const float* __restrict__ query, const float* __restrict__ key,
                const float* __restrict__ value,
                const unsigned short* __restrict__ Wqb, const unsigned short* __restrict__ Wkb,
                const unsigned short* __restrict__ Wvb,
                const float* __restrict__ bq, const float* __restrict__ bk,
                const float* __restrict__ bv,
                unsigned short* __restrict__ Qb, unsigned short* __restrict__ Kpp,
                unsigned short* __restrict__ Vtt) {
  __shared__ float          Asf[2 * 128 * 32];  // fp32 A double buffer: 32 KB
  __shared__ unsigned short Bs[2 * 128 * 32];   // bf16 W double buffer: 16 KB
  const int tid  = threadIdx.x;
  const int wave = tid >> 6, lane = tid & 63;
  const int l16  = lane & 15, quad = lane >> 4;
  const int bm = blockIdx.x * 128;
  const int wm = (wave & 1) * 64, wn = (wave >> 1) * 64;
  const int y = blockIdx.y;

  const float *A;
  const unsigned short *W;
  const float* bias;
  unsigned short* out;
  int bn, mode, Nn;
  float scale;
  if (y < 16)      { A = query; W = Wqb; bias = bq; out = Qb;  bn = y * 128;        mode = 0; Nn = 2048; scale = QSC;  }
  else if (y < 20) { A = key;   W = Wkb; bias = bk; out = Kpp; bn = (y - 16) * 128; mode = 0; Nn = 512;  scale = 1.0f; }
  else             { A = value; W = Wvb; bias = bv; out = Vtt; bn = (y - 20) * 128; mode = 1; Nn = 512;  scale = 1.0f; }

  f32x4 acc[4][4] = {};
  kloop_f32A(A, W, Asf, Bs, bm, bn, wm, wn, tid, l16, quad, acc);

  if (mode == 0) {
#pragma unroll
    for (int mi = 0; mi < 4; ++mi)
#pragma unroll
      for (int ni = 0; ni < 4; ++ni) {
        int col = bn + wn + ni * 16 + l16;
        float bb = bias[col];
        int row0 = bm + wm + mi * 16 + quad * 4;
#pragma unroll
        for (int r = 0; r < 4; ++r)
          out[(size_t)(row0 + r) * Nn + col] = f2bf((acc[mi][ni][r] + bb) * scale);
      }
  } else {  // V: transposed per batch -> Vt[(b*KVE + col)*N + s]
#pragma unroll
    for (int mi = 0; mi < 4; ++mi)
#pragma unroll
      for (int ni = 0; ni < 4; ++ni) {
        int col = bn + wn + ni * 16 + l16;
        float bb = bias[col];
        int row0 = bm + wm + mi * 16 + quad * 4;
        int b = row0 >> 11, s = row0 & 2047;
        ushort4 o;
        o.x = f2bf(acc[mi][ni][0] + bb);
        o.y = f2bf(acc[mi][ni][1] + bb);
        o.z = f2bf(acc[mi][ni][2] + bb);
        o.w = f2bf(acc[mi][ni][3] + bb);
        *(ushort4*)(out + (size_t)(b * KVE_ + col) * N_ + s) = o;
      }
  }
}

// ---------------- output projection (fp32 out, R4-verified) ----------------
__global__ __launch_bounds__(256, 3)
void gemm_out(const unsigned short* __restrict__ A, const unsigned short* __restrict__ W,
              const float* __restrict__ bias, float* __restrict__ Cout) {
  __shared__ unsigned short As[2 * 128 * 32];
  __shared__ unsigned short Bs[2 * 128 * 32];
  const int tid  = threadIdx.x;
  const int wave = tid >> 6, lane = tid & 63;
  const int l16  = lane & 15, quad = lane >> 4;
  const int bm = blockIdx.x * 128, bn = blockIdx.y * 128;
  const int wm = (wave & 1) * 64, wn = (wave >> 1) * 64;

  f32x4 acc[4][4] = {};
  gemm_kloop(A, W, As, Bs, bm, bn, E_, wm, wn, tid, l16, quad, acc);

#pragma unroll
  for (int mi = 0; mi < 4; ++mi)
#pragma unroll
    for (int ni = 0; ni < 4; ++ni) {
      int col = bn + wn + ni * 16 + l16;
      float bb = bias[col];
      int row0 = bm + wm + mi * 16 + quad * 4;
#pragma unroll
      for (int r = 0; r < 4; ++r)
        Cout[(size_t)(row0 + r) * E_ + col] = acc[mi][ni][r] + bb;
    }
}

// ---------------- Flash attention (R6-verified: R1 structure + T5 setprio) ----
// 32-key KV tiles, LDS 32 KB, each wave owns 16 q rows x full key range.
// Grid (32,32); launch_bounds(256,4). Measured: 81.4 us, VGPR 56, no spill.
__global__ __launch_bounds__(256, 4)
void attn_gqa(const unsigned short* __restrict__ Qp,
              const unsigned short* __restrict__ Kp,
              const unsigned short* __restrict__ Vt,
              unsigned short* __restrict__ Ob,
              const int* __restrict__ is_causal_p) {
  __shared__ unsigned short lds[2][8192];  // [buf][ K:4096 shorts | V:4096 shorts ] = 32KB

  const int tid  = threadIdx.x;
  const int wave = tid >> 6, lane = tid & 63;
  const int l16  = lane & 15, quad = lane >> 4;
  const int bh = blockIdx.y;
  const int u  = (blockIdx.x + bh) & 31;
  const int qt = (u < 16) ? u : 47 - u;   // 64-row q-tile; balanced per-CU sum
  const int b = bh >> 4, hq = bh & 15, hk = hq >> 2;
  const int causal = *is_causal_p;

  const unsigned short* Kbase = Kp + (size_t)b * N_ * KVE_ + hk * D_;
  const unsigned short* Vbase = Vt + (size_t)(b * KVE_ + hk * D_) * N_;

  const int nt = causal ? 2 * qt + 2 : (N_ / 32);  // 32-key tiles
  const int qw = qt * 64 + wave * 16;              // wave's 16-q window start

  auto stage = [&](int t, int buf) {
    int s0 = t * 32;
    unsigned short* Kd = &lds[buf][0];
    unsigned short* Vd = &lds[buf][4096];
#pragma unroll
    for (int r = 0; r < 2; ++r) {
      int idx = r * 256 + tid;
      int s = (idx >> 8) * 16 + (idx & 15);
      int d = ((idx >> 6) & 3) * 32 + ((idx >> 4) & 3) * 8;
      g2l16(Kbase + (size_t)(s0 + s) * KVE_ + d, Kd + (size_t)idx * 8);
    }
#pragma unroll
    for (int r = 0; r < 2; ++r) {
      int idx = r * 256 + tid;
      int d = (idx >> 6) * 16 + (idx & 15);
      int sc = ((idx >> 4) & 3) * 8;
      g2l16(Vbase + (size_t)d * N_ + s0 + sc, Vd + (size_t)idx * 8);
    }
  };

  // Q fragments (B-operand: n=l16 -> q, k=quad*8+j -> d), exp2-scaled already
  bf16x8 qf[4];
#pragma unroll
  for (int kk = 0; kk < 4; ++kk)
    qf[kk] = *(const bf16x8*)(Qp + (size_t)(b * N_ + qw + l16) * E_ +
                              hq * D_ + kk * 32 + quad * 8);

  f32x4 o[8] = {};
  float tsum = 0.f;

  stage(0, 0);
  __syncthreads();

  for (int t = 0; t < nt; ++t) {
    if (t + 1 < nt) stage(t + 1, (t + 1) & 1);  // overlaps compute(t)
    const unsigned short* Kb = &lds[t & 1][0];
    const unsigned short* Vb = &lds[t & 1][4096];
    const int sw = t * 32;
    const bool active = !causal || (sw <= qw + 15);  // wave-uniform

    if (active) {
      // S^T = K Q^T : rows s = sw + ni*16+quad*4+r, cols q = qw + l16
      f32x4 sa[2] = {};
      __builtin_amdgcn_s_setprio(1);
#pragma unroll
      for (int kk = 0; kk < 4; ++kk) {
        bf16x8 kf0 = *(const bf16x8*)(Kb + ((kk)     * 64 + lane) * 8);
        bf16x8 kf1 = *(const bf16x8*)(Kb + ((4 + kk) * 64 + lane) * 8);
        sa[0] = __builtin_amdgcn_mfma_f32_16x16x32_bf16(kf0, qf[kk], sa[0], 0, 0, 0);
        sa[1] = __builtin_amdgcn_mfma_f32_16x16x32_bf16(kf1, qf[kk], sa[1], 0, 0, 0);
      }
      __builtin_amdgcn_s_setprio(0);

      if (causal && sw + 31 > qw) {  // diagonal overlap: mask s > q
        int q = qw + l16;
#pragma unroll
        for (int ni = 0; ni < 2; ++ni) {
          int sbase = sw + ni * 16 + quad * 4;
#pragma unroll
          for (int r = 0; r < 4; ++r)
            if (sbase + r > q) sa[ni][r] = -3.0e38f;
        }
      }

      // P = exp2(S) (no max subtraction), pack to bf16 pairs in-register
      uint32_t pk[2][2];
#pragma unroll
      for (int ni = 0; ni < 2; ++ni) {
#pragma unroll
        for (int r = 0; r < 4; ++r) {
          float e = __builtin_amdgcn_exp2f(sa[ni][r]);
          tsum += e;
          sa[ni][r] = e;
        }
        pk[ni][0] = pack_bf2(sa[ni][0], sa[ni][1]);
        pk[ni][1] = pack_bf2(sa[ni][2], sa[ni][3]);
      }

      // B-operand P[k=quad*8+j][n=l16] via shuffle network (unchanged mapping)
      union { bf16x8 v; uint32_t w[4]; } pb;
#pragma unroll
      for (int h = 0; h < 4; ++h) {
        int src = ((quad & 1) * 2 + (h >> 1)) * 16 + l16;
        uint32_t v0 = __shfl(pk[0][h & 1], src);
        uint32_t v1 = __shfl(pk[1][h & 1], src);
        pb.w[h] = (quad & 2) ? v1 : v0;
      }

      // O^T += V^T[:, sw:sw+32] P^T[sw:sw+32, :] — one K=32 MFMA step per d-block
      bf16x8 vf[8];
#pragma unroll
      for (int n8 = 0; n8 < 8; ++n8)
        vf[n8] = *(const bf16x8*)(Vb + (n8 * 64 + lane) * 8);
      __builtin_amdgcn_s_setprio(1);
#pragma unroll
      for (int n8 = 0; n8 < 8; ++n8)
        o[n8] = __builtin_amdgcn_mfma_f32_16x16x32_bf16(vf[n8], pb.v, o[n8], 0, 0, 0);
      __builtin_amdgcn_s_setprio(0);
    }
    __syncthreads();  // drains stage(t+1); protects buffer reuse
  }

  // ---- epilogue: pure-register; full row-sum via quad reduction ----
  float lt = tsum;
  lt += __shfl_xor(lt, 16);
  lt += __shfl_xor(lt, 32);
  float inv = 1.0f / lt;
  int q = qw + l16;
#pragma unroll
  for (int n8 = 0; n8 < 8; ++n8) {
    ushort4 st;
    st.x = f2bf(o[n8][0] * inv);
    st.y = f2bf(o[n8][1] * inv);
    st.z = f2bf(o[n8][2] * inv);
    st.w = f2bf(o[n8][3] * inv);
    *(ushort4*)(Ob + (size_t)(b * N_ + q) * E_ + hq * D_ + n8 * 16 + quad * 4) = st;
  }
}

// ---------------- host ----------------
extern "C" void kernel_launch(void* const* d_in, const int* in_sizes, int n_in,
                              void* d_out, int out_size, void* d_ws, size_t ws_size,
                              hipStream_t stream) {
  const float* query = (const float*)d_in[0];
  const float* key   = (const float*)d_in[1];
  const float* value = (const float*)d_in[2];
  const float* Wq = (const float*)d_in[3];
  const float* bq = (const float*)d_in[4];
  const float* Wk = (const float*)d_in[5];
  const float* bk = (const float*)d_in[6];
  const float* Wv = (const float*)d_in[7];
  const float* bv = (const float*)d_in[8];
  const float* Wo = (const float*)d_in[9];
  const float* bo = (const float*)d_in[10];
  const int* is_causal = (const int*)d_in[11];

  char* ws = (char*)d_ws;
  size_t off = 0;
  auto alloc = [&](size_t bytes) {
    char* p = ws + off;
    off += (bytes + 255) & ~(size_t)255;
    return p;
  };
  // NOTE: Wqb..Wob must stay contiguous in this order (cast_w writes one region)
  unsigned short* Wqb = (unsigned short*)alloc((size_t)E_ * E_ * 2);
  unsigned short* Wkb = (unsigned short*)alloc((size_t)KVE_ * E_ * 2);
  unsigned short* Wvb = (unsigned short*)alloc((size_t)KVE_ * E_ * 2);
  unsigned short* Wob = (unsigned short*)alloc((size_t)E_ * E_ * 2);
  unsigned short* Qb  = (unsigned short*)alloc((size_t)MTOT * E_ * 2);
  unsigned short* Kpp = (unsigned short*)alloc((size_t)MTOT * KVE_ * 2);
  unsigned short* Vtt = (unsigned short*)alloc((size_t)MTOT * KVE_ * 2);
  unsigned short* Ob  = (unsigned short*)alloc((size_t)MTOT * E_ * 2);
  (void)ws_size; (void)n_in; (void)in_sizes; (void)out_size;

  dim3 blk(256);
  cast_w<<<dim3(10240), blk, 0, stream>>>(Wq, Wk, Wv, Wo, Wqb);
  proj_fused<<<dim3(32, 24), blk, 0, stream>>>(query, key, value, Wqb, Wkb, Wvb,
                                               bq, bk, bv, Qb, Kpp, Vtt);
  attn_gqa<<<dim3(32, 32), blk, 0, stream>>>(Qb, Kpp, Vtt, Ob, is_causal);
  gemm_out<<<dim3(32, 16), blk, 0, stream>>>(Ob, Wob, bo, (float*)d_out);
}